// Round 3
// baseline (22961.913 us; speedup 1.0000x reference)
//
#include <hip/hip_runtime.h>
#include <hip/hip_bf16.h>

typedef _Float16 f16x2 __attribute__((ext_vector_type(2)));

#define HID 300
#define NSEQ 64
#define NROWS 4096   // B*N = 64*64

__device__ __forceinline__ float sigm(float x){ return 1.f/(1.f+__expf(-x)); }

__device__ __forceinline__ float fdot2a(f16x2 a, f16x2 b, float c){
#if __has_builtin(__builtin_amdgcn_fdot2)
  return __builtin_amdgcn_fdot2(a, b, c, false);
#else
  return c + (float)a.x*(float)b.x + (float)a.y*(float)b.y;
#endif
}

// ---------------------------------------------------------------------------
// Serial-path weight repack: f32 -> fp16 pairs, [kg][outs][4 pairs] layout.
// W_M4: per layer [38][1800][4]; rows 0..899 = whh_c, 900..1799 = wih_p.
// WrT4: per layer [38][600][4]; row t = d*2+hh (hh=0 -> wr0 row d, 1 -> wr1).
// Cols padded 300->304.
// ---------------------------------------------------------------------------
__global__ void convert_kernel(const float* __restrict__ whh_c, const float* __restrict__ wih_p,
    const float* __restrict__ wr0, const float* __restrict__ wr1,
    f16x2* __restrict__ W_M4, f16x2* __restrict__ WrT4)
{
  const int NA = 4*38*1800*4;
  const int NB = 4*38*600*4;
  for (int idx = blockIdx.x*blockDim.x + threadIdx.x; idx < NA+NB; idx += gridDim.x*blockDim.x){
    if (idx < NA){
      int l    = idx/(38*1800*4);
      int rem  = idx - l*(38*1800*4);
      int kg   = rem/(1800*4);
      int rem2 = rem - kg*(1800*4);
      int o = rem2>>2, s = rem2&3;
      int c = (kg*4+s)*2;
      float v0=0.f, v1=0.f;
      if (c < 300){
        const float* src = (o<900) ? (whh_c + ((size_t)l*900+o)*300)
                                   : (wih_p + ((size_t)l*900+(o-900))*300);
        v0 = src[c]; v1 = src[c+1];
      }
      f16x2 t; t.x=(_Float16)v0; t.y=(_Float16)v1;
      W_M4[idx] = t;
    } else {
      int j    = idx - NA;
      int l    = j/(38*600*4);
      int rem  = j - l*(38*600*4);
      int kg   = rem/(600*4);
      int rem2 = rem - kg*(600*4);
      int t6 = rem2>>2, s = rem2&3;
      int d = t6>>1, hh = t6&1;
      int c = (kg*4+s)*2;
      float v0=0.f, v1=0.f;
      if (c < 300){
        const float* src = hh ? (wr1 + ((size_t)l*300+d)*300)
                              : (wr0 + ((size_t)l*300+d)*300);
        v0 = src[c]; v1 = src[c+1];
      }
      f16x2 t; t.x=(_Float16)v0; t.y=(_Float16)v1;
      WrT4[j] = t;
    }
  }
}

// ---------------------------------------------------------------------------
// Head weight repack + sync-counter zeroing (runs every launch).
// W_14: [318 kg][304 o][4 pairs]; segments: seg0..4 = Hcat cols seg*300 (38 kg
// each), seg5..6 = feat cols 1500+(seg-5)*512 (64 kg each).
// W_24: [38][304][4].  syncc: 4*64*64 ints zeroed.
// ---------------------------------------------------------------------------
__global__ void convert_head_kernel(const float* __restrict__ w1, const float* __restrict__ w2,
    f16x2* __restrict__ W_14, f16x2* __restrict__ W_24, int* __restrict__ syncc)
{
  const int N1 = 318*304*4;
  const int N2 = 38*304*4;
  const int NS = 4*64*64;
  for (int idx = blockIdx.x*blockDim.x + threadIdx.x; idx < N1+N2+NS; idx += gridDim.x*blockDim.x){
    if (idx < N1){
      int kgg = idx/(304*4);
      int rem = idx - kgg*(304*4);
      int o = rem>>2, s = rem&3;
      int segbase, seglen, kgl;
      if (kgg < 190){ int seg = kgg/38; kgl = kgg - seg*38; segbase = seg*300; seglen = 300; }
      else { int kk = kgg-190; int sf = kk>>6; kgl = kk&63; segbase = 1500 + sf*512; seglen = 512; }
      int c = (kgl*4+s)*2;
      float v0=0.f, v1=0.f;
      if (o < 300 && c < seglen){
        v0 = w1[(size_t)o*2524 + segbase + c];
        if (c+1 < seglen) v1 = w1[(size_t)o*2524 + segbase + c + 1];
      }
      f16x2 t; t.x=(_Float16)v0; t.y=(_Float16)v1;
      W_14[idx] = t;
    } else if (idx < N1+N2){
      int j = idx - N1;
      int kg = j/(304*4);
      int rem = j - kg*(304*4);
      int o = rem>>2, s = rem&3;
      int c = (kg*4+s)*2;
      float v0=0.f, v1=0.f;
      if (o < 300 && c < 300){ v0 = w2[(size_t)o*300+c]; v1 = w2[(size_t)o*300+c+1]; }
      f16x2 t; t.x=(_Float16)v0; t.y=(_Float16)v1;
      W_24[j] = t;
    } else {
      syncc[idx - N1 - N2] = 0;
    }
  }
}

// ---------------------------------------------------------------------------
// H0 = relu(features @ w_in^T + b_in) : (4096,1024)x(1024,300) -> f32
// ---------------------------------------------------------------------------
__global__ __launch_bounds__(256) void h0_kernel(const float* __restrict__ feat,
    const float* __restrict__ w_in, const float* __restrict__ b_in, float* __restrict__ H0)
{
  const int tid = threadIdx.x;
  const int r0  = blockIdx.x*16;
  __shared__ float X[16*512];
  float acc[2][16];
  #pragma unroll
  for (int a=0;a<2;a++)
    #pragma unroll
    for (int r=0;r<16;r++) acc[a][r]=0.f;

  for (int c=0;c<2;c++){
    for (int t=tid; t<16*512; t+=256){
      int r=t>>9, k=t&511;
      X[t] = feat[(size_t)(r0+r)*1024 + c*512 + k];
    }
    __syncthreads();
    #pragma unroll
    for (int oo=0;oo<2;oo++){
      int o = tid + oo*256;
      if (o < HID){
        const float* wrow = w_in + (size_t)o*1024 + c*512;
        for (int k=0;k<512;k+=4){
          float4 w = *(const float4*)(wrow+k);
          #pragma unroll
          for (int r=0;r<16;r++)
            acc[oo][r] += w.x*X[r*512+k] + w.y*X[r*512+k+1]
                        + w.z*X[r*512+k+2] + w.w*X[r*512+k+3];
        }
      }
    }
    __syncthreads();
  }
  #pragma unroll
  for (int oo=0;oo<2;oo++){
    int o = tid + oo*256;
    if (o < HID){
      float bb = b_in[o];
      for (int r=0;r<16;r++)
        H0[(size_t)(r0+r)*HID + o] = fmaxf(acc[oo][r]+bb, 0.f);
    }
  }
}

// ---------------------------------------------------------------------------
// Per-layer precompute (f32, unchanged from round 2).
// ---------------------------------------------------------------------------
__global__ __launch_bounds__(256) void pre_kernel(const float* __restrict__ Hin,
    float* __restrict__ pre, float* __restrict__ qd,
    const float* __restrict__ wih_c, const float* __restrict__ whh_p,
    const float* __restrict__ bih_c, const float* __restrict__ bhh_p,
    const float* __restrict__ wq)
{
  const int tid = threadIdx.x;
  const int r0  = blockIdx.x*16;
  __shared__ float X[16*304];
  for (int t=tid; t<16*HID; t+=256){
    int r=t/HID, k=t-r*HID;
    X[r*304+k] = Hin[(size_t)(r0+r)*HID + k];
  }
  __syncthreads();
  for (int o=tid; o<1800; o+=256){
    const float* wrow; float bias;
    if (o < 900){ wrow = wih_c + (size_t)o*HID;        bias = bih_c[o]; }
    else        { wrow = whh_p + (size_t)(o-900)*HID;  bias = bhh_p[o-900]; }
    float acc[16];
    #pragma unroll
    for (int r=0;r<16;r++) acc[r]=0.f;
    for (int k=0;k<HID;k+=4){
      float4 w = *(const float4*)(wrow+k);
      #pragma unroll
      for (int r=0;r<16;r++)
        acc[r] += w.x*X[r*304+k] + w.y*X[r*304+k+1]
                + w.z*X[r*304+k+2] + w.w*X[r*304+k+3];
    }
    #pragma unroll
    for (int r=0;r<16;r++)
      pre[(size_t)(r0+r)*1800 + o] = acc[r] + bias;
  }
  if (tid < 16){
    float s=0.f; const float* x=&X[tid*304];
    for (int k=0;k<HID;k++) s += wq[k]*x[k];
    qd[r0+tid] = s;
  }
}

// ---------------------------------------------------------------------------
// Sequential scan, 4 WGs per chain (256 WGs x 512 thr).
// Slice sl computes gates rows [450*sl, 450*sl+450); softmax/u/M/GRU replicated.
// One device-scope counter sync per step; double-buffered exchange.
// ---------------------------------------------------------------------------
__global__ __launch_bounds__(512) void scan_kernel(
  const float* __restrict__ Hin, float* __restrict__ Hout,
  const float* __restrict__ pre, const float* __restrict__ qd,
  const f16x2* __restrict__ Wm, const f16x2* __restrict__ Wrt,
  const float* __restrict__ bhh_c, const float* __restrict__ bih_p,
  const float* __restrict__ wk, const float* __restrict__ gat_b, int layer,
  const int* __restrict__ speakers, float* __restrict__ xchg, int* __restrict__ syncc)
{
  __shared__ _Float16 Hh[NSEQ][304];
  __shared__ float gates[1800];
  __shared__ float Mf[HID];
  __shared__ f16x2 Mh[152];
  __shared__ f16x2 u01h[304];
  __shared__ float partM[600];
  __shared__ float wgt[NSEQ];
  __shared__ float kd[NSEQ];
  __shared__ float qs[NSEQ];
  __shared__ float red[320];
  __shared__ int   spk[NSEQ];
  __shared__ int   startA[NSEQ];

  const int tid   = threadIdx.x;
  const int chain = blockIdx.x & 63;   // 4 WGs of a chain: bid, bid+64, ... (same XCD under round-robin)
  const int sl    = blockIdx.x >> 6;   // slice 0..3
  const int base  = chain*NSEQ;
  const float* preB = pre + (size_t)base*1800;
  const float* HinB = Hin + (size_t)base*HID;
  float* HoutB      = Hout + (size_t)base*HID;
  const uint4* Wm4  = (const uint4*)Wm;
  const uint4* Wr4  = (const uint4*)Wrt;
  const float gb = gat_b[layer];
  int*   cnt = syncc + ((size_t)layer*64 + chain)*64;   // 256B-spaced counter
  float* xb0 = xchg + (size_t)chain*3600;               // 2 x 1800 exchange

  float bcr=0,bcz=0,bcn=0,bpr=0,bpz=0,bpn=0,wkv=0;
  if (tid < HID){
    bcr=bhh_c[tid]; bcz=bhh_c[300+tid]; bcn=bhh_c[600+tid];
    bpr=bih_p[tid]; bpz=bih_p[300+tid]; bpn=bih_p[600+tid];
    wkv=wk[tid];
  }
  if (tid < NSEQ){ spk[tid] = speakers[base+tid]; qs[tid] = qd[base+tid]; }
  if (tid >= 300 && tid < 320) red[tid] = 0.f;
  if (tid >= 300 && tid < 304){
    ((_Float16*)Mh)[tid]        = (_Float16)0.f;
    ((_Float16*)u01h)[tid]      = (_Float16)0.f;
    ((_Float16*)u01h)[304+tid]  = (_Float16)0.f;
  }
  __syncthreads();
  if (tid < NSEQ){
    int s = 0;
    for (int j=tid-1; j>=0; --j) if (spk[j]==spk[tid]){ s=j; break; }
    startA[tid] = s;
  }
  // i = 0
  if (tid < HID){
    const float* p0 = preB;
    float r  = sigm(p0[tid] + bcr);
    float z  = sigm(p0[300+tid] + bcz);
    float n  = tanhf(p0[600+tid] + r*bcn);
    float C0 = (1.f-z)*n;
    float rp = sigm(bpr + p0[900+tid]);
    float zp = sigm(bpz + p0[1200+tid]);
    float np = tanhf(bpn + rp*p0[1500+tid]);
    float x0 = HinB[tid];
    float P0 = (1.f-zp)*np + zp*x0;
    float h  = C0 + P0;
    if (sl==0) HoutB[tid] = h;
    Hh[0][tid] = (_Float16)h;
    red[tid]   = h*wkv;
  }
  __syncthreads();
  if (tid < 64){
    float s = red[tid]+red[tid+64]+red[tid+128]+red[tid+192]+red[tid+256];
    #pragma unroll
    for (int o=32;o>0;o>>=1) s += __shfl_xor(s,o);
    if (tid==0) kd[0]=s;
  }

  for (int i=1; i<NSEQ; ++i){
    // prefetch pre row i + Hin row i (consumed in GRU phase)
    float pr0=0,pr1=0,pr2=0,pr3=0,pr4=0,pr5=0,qv=0;
    if (tid < HID){
      const float* p = preB + (size_t)i*1800;
      pr0=p[tid]; pr1=p[300+tid]; pr2=p[600+tid];
      pr3=p[900+tid]; pr4=p[1200+tid]; pr5=p[1500+tid];
      qv = HinB[(size_t)i*HID + tid];
    }
    __syncthreads();   // kd[i-1], Hh[i-1] visible
    // A: masked softmax (one wave), replicated
    if (tid < 64){
      const int st = startA[i];
      const bool in = (tid>=st) && (tid<i);
      const float q = qs[i];
      float a = in ? (q + kd[tid] + gb) : -3.0e38f;
      float m = a;
      #pragma unroll
      for (int o=32;o>0;o>>=1) m = fmaxf(m, __shfl_xor(m,o));
      float e = in ? __expf(a-m) : 0.f;
      float ssum = e;
      #pragma unroll
      for (int o=32;o>0;o>>=1) ssum += __shfl_xor(ssum,o);
      wgt[tid] = e/ssum;
    }
    __syncthreads();
    // B: u0/u1 weighted history sums (600 outs over 512 thr), replicated
    {
      const int st = startA[i]; const int ms = spk[i];
      #pragma unroll
      for (int pass=0; pass<2; pass++){
        int t = tid + pass*512;
        if (t < 600){
          const int d  = (t<300)? t : (t-300);
          const int wh = (t>=300);
          float u=0.f;
          for (int j=st;j<i;++j){
            float sel = ((spk[j]==ms) != (wh!=0)) ? 1.f : 0.f;
            u += sel*wgt[j]*(float)Hh[j][d];
          }
          ((_Float16*)u01h)[(wh?304:0) + d] = (_Float16)u;
        }
      }
    }
    __syncthreads();
    // C: partial M = wr0@u0 + wr1@u1 (600 rows over 512 thr), replicated
    {
      #pragma unroll
      for (int pass=0; pass<2; pass++){
        int t = tid + pass*512;
        if (t < 600){
          const int hh = t&1;
          const f16x2* uu = (const f16x2*)u01h + hh*152;
          float a0=0,a1=0,a2=0,a3=0;
          for (int kg=0;kg<38;kg++){
            union { uint4 u; f16x2 h[4]; } v;
            v.u = Wr4[(size_t)kg*600 + t];
            a0=fdot2a(v.h[0],uu[kg*4+0],a0);
            a1=fdot2a(v.h[1],uu[kg*4+1],a1);
            a2=fdot2a(v.h[2],uu[kg*4+2],a2);
            a3=fdot2a(v.h[3],uu[kg*4+3],a3);
          }
          partM[t] = (a0+a1)+(a2+a3);
        }
      }
    }
    __syncthreads();
    if (tid < HID){
      float m = partM[2*tid]+partM[2*tid+1];
      Mf[tid]=m; ((_Float16*)Mh)[tid]=(_Float16)m;
    }
    __syncthreads();
    // D: gates slice = Wm rows [450*sl, 450*sl+450) @ M -> exchange buffer
    {
      float* xb = xb0 + (size_t)(i&1)*1800;
      if (tid < 450){
        const int r = 450*sl + tid;
        float a0=0,a1=0,a2=0,a3=0;
        for (int kg=0;kg<38;kg++){
          union { uint4 u; f16x2 h[4]; } v;
          v.u = Wm4[(size_t)kg*1800 + r];
          a0=fdot2a(v.h[0],Mh[kg*4+0],a0);
          a1=fdot2a(v.h[1],Mh[kg*4+1],a1);
          a2=fdot2a(v.h[2],Mh[kg*4+2],a2);
          a3=fdot2a(v.h[3],Mh[kg*4+3],a3);
        }
        __hip_atomic_store(xb + r, (a0+a1)+(a2+a3),
                           __ATOMIC_RELAXED, __HIP_MEMORY_SCOPE_AGENT);
      }
      // sync: one counter add per WG per step; spin to 4*i (monotonic)
      __threadfence();
      __syncthreads();
      if (tid == 0){
        __hip_atomic_fetch_add(cnt, 1, __ATOMIC_ACQ_REL, __HIP_MEMORY_SCOPE_AGENT);
        while (__hip_atomic_load(cnt, __ATOMIC_ACQUIRE, __HIP_MEMORY_SCOPE_AGENT) < 4*i)
          __builtin_amdgcn_s_sleep(2);
      }
      __syncthreads();
      __threadfence();
      for (int t=tid; t<1800; t+=512)
        gates[t] = __hip_atomic_load(xb + t, __ATOMIC_RELAXED, __HIP_MEMORY_SCOPE_AGENT);
    }
    __syncthreads();
    // E: GRU combine, replicated; slice 0 writes Hout
    if (tid < HID){
      const float M = Mf[tid];
      float r  = sigm(pr0 + gates[tid] + bcr);
      float z  = sigm(pr1 + gates[300+tid] + bcz);
      float n  = tanhf(pr2 + r*(gates[600+tid]+bcn));
      float C  = (1.f-z)*n + z*M;
      float rp = sigm(gates[900+tid]+bpr + pr3);
      float zp = sigm(gates[1200+tid]+bpz + pr4);
      float np = tanhf(gates[1500+tid]+bpn + rp*pr5);
      float P  = (1.f-zp)*np + zp*qv;
      float h  = C + P;
      if (sl==0) HoutB[(size_t)i*HID + tid] = h;
      Hh[i][tid] = (_Float16)h;
      red[tid] = h*wkv;
    }
    __syncthreads();
    // F: kd[i] = wk . H1[i]
    if (tid < 64){
      float s = red[tid]+red[tid+64]+red[tid+128]+red[tid+192]+red[tid+256];
      #pragma unroll
      for (int o=32;o>0;o>>=1) s += __shfl_xor(s,o);
      if (tid==0) kd[i]=s;
    }
  }
}

// ---------------------------------------------------------------------------
// Head with fp16-dot2 GEMMs; segments unrolled.
// ---------------------------------------------------------------------------
__global__ __launch_bounds__(256) void head_kernel(
  const float* __restrict__ H0, const float* __restrict__ Hl1,
  const float* __restrict__ Hl2, const float* __restrict__ Hl3,
  const float* __restrict__ Hl4, const float* __restrict__ feat,
  const f16x2* __restrict__ W14, const float* __restrict__ b1,
  const f16x2* __restrict__ W24, const float* __restrict__ b2,
  const float* __restrict__ w3, const float* __restrict__ b3,
  float* __restrict__ out)
{
  const int tid = threadIdx.x;
  const int r0  = blockIdx.x*16;
  __shared__ f16x2 Xh[16*256];
  __shared__ _Float16 h1h[16*304];
  __shared__ float S2[16*304];
  const uint4* W14u = (const uint4*)W14;
  const uint4* W24u = (const uint4*)W24;

  float acc0[16], acc1[16];
  #pragma unroll
  for (int r=0;r<16;r++){ acc0[r]=0.f; acc1[r]=0.f; }
  const int o  = tid;
  const int o2 = tid + 256;
  const bool has2 = (o2 < 300);

  #pragma unroll
  for (int seg=0; seg<7; seg++){
    const float* src = (seg==0)?H0:(seg==1)?Hl1:(seg==2)?Hl2:(seg==3)?Hl3:(seg==4)?Hl4:feat;
    if (seg < 5){
      for (int t=tid; t<16*152; t+=256){
        int r=t/152, p=t-r*152, c=2*p;
        float v0 = (c<300)? src[(size_t)(r0+r)*300 + c] : 0.f;
        float v1 = (c+1<300)? src[(size_t)(r0+r)*300 + c+1] : 0.f;
        f16x2 h; h.x=(_Float16)v0; h.y=(_Float16)v1;
        Xh[r*256+p] = h;
      }
    } else {
      const int cb = (seg-5)*512;
      for (int t=tid; t<16*256; t+=256){
        int r=t>>8, p=t&255;
        float v0 = src[(size_t)(r0+r)*1024 + cb + 2*p];
        float v1 = src[(size_t)(r0+r)*1024 + cb + 2*p+1];
        f16x2 h; h.x=(_Float16)v0; h.y=(_Float16)v1;
        Xh[r*256+p] = h;
      }
    }
    __syncthreads();
    const int kgs = (seg<5)?38:64;
    const int kgo = (seg<5)? seg*38 : 190+(seg-5)*64;
    if (o < 300){
      for (int kg=0; kg<kgs; kg++){
        union { uint4 u; f16x2 h[4]; } a, b;
        a.u = W14u[(size_t)(kgo+kg)*304 + o];
        if (has2) b.u = W14u[(size_t)(kgo+kg)*304 + o2];
        #pragma unroll
        for (int r=0;r<16;r++){
          const f16x2* xp = &Xh[r*256 + kg*4];
          float t0 = fdot2a(a.h[0], xp[0], 0.f);
          t0 = fdot2a(a.h[1], xp[1], t0);
          t0 = fdot2a(a.h[2], xp[2], t0);
          t0 = fdot2a(a.h[3], xp[3], t0);
          acc0[r] += t0;
          if (has2){
            float t1 = fdot2a(b.h[0], xp[0], 0.f);
            t1 = fdot2a(b.h[1], xp[1], t1);
            t1 = fdot2a(b.h[2], xp[2], t1);
            t1 = fdot2a(b.h[3], xp[3], t1);
            acc1[r] += t1;
          }
        }
      }
    }
    __syncthreads();
  }
  // h1 = relu(. + b1) -> fp16 LDS
  if (o < 300){
    float bb = b1[o];
    #pragma unroll
    for (int r=0;r<16;r++) h1h[r*304+o] = (_Float16)fmaxf(acc0[r]+bb, 0.f);
  }
  if (has2){
    float bb = b1[o2];
    #pragma unroll
    for (int r=0;r<16;r++) h1h[r*304+o2] = (_Float16)fmaxf(acc1[r]+bb, 0.f);
  }
  if (tid < 4){
    #pragma unroll
    for (int r=0;r<16;r++) h1h[r*304+300+tid] = (_Float16)0.f;
  }
  __syncthreads();
  // h2 = relu(h1 @ w2^T + b2)
  #pragma unroll
  for (int r=0;r<16;r++){ acc0[r]=0.f; acc1[r]=0.f; }
  if (o < 300){
    for (int kg=0; kg<38; kg++){
      union { uint4 u; f16x2 h[4]; } a, b;
      a.u = W24u[(size_t)kg*304 + o];
      if (has2) b.u = W24u[(size_t)kg*304 + o2];
      #pragma unroll
      for (int r=0;r<16;r++){
        const f16x2* xp = (const f16x2*)&h1h[r*304] + kg*4;
        float t0 = fdot2a(a.h[0], xp[0], 0.f);
        t0 = fdot2a(a.h[1], xp[1], t0);
        t0 = fdot2a(a.h[2], xp[2], t0);
        t0 = fdot2a(a.h[3], xp[3], t0);
        acc0[r] += t0;
        if (has2){
          float t1 = fdot2a(b.h[0], xp[0], 0.f);
          t1 = fdot2a(b.h[1], xp[1], t1);
          t1 = fdot2a(b.h[2], xp[2], t1);
          t1 = fdot2a(b.h[3], xp[3], t1);
          acc1[r] += t1;
        }
      }
    }
  }
  __syncthreads();
  if (o < 300){
    float bb = b2[o];
    #pragma unroll
    for (int r=0;r<16;r++) S2[r*304+o] = fmaxf(acc0[r]+bb, 0.f);
  }
  if (has2){
    float bb = b2[o2];
    #pragma unroll
    for (int r=0;r<16;r++) S2[r*304+o2] = fmaxf(acc1[r]+bb, 0.f);
  }
  __syncthreads();
  // logits (7 per row), f32
  if (tid < 16*7){
    int r = tid/7, c = tid - r*7;
    float s = b3[c];
    const float* wrow = w3 + (size_t)c*HID;
    for (int k=0;k<HID;k++) s += wrow[k]*S2[r*304+k];
    out[(size_t)(r0+r)*7 + c] = s;
  }
}

// ---------------------------------------------------------------------------
extern "C" void kernel_launch(void* const* d_in, const int* in_sizes, int n_in,
                              void* d_out, int out_size, void* d_ws, size_t ws_size,
                              hipStream_t stream)
{
  (void)in_sizes; (void)n_in; (void)out_size; (void)ws_size;
  const float* feat  = (const float*)d_in[0];
  const int*   spk   = (const int*)d_in[1];
  const float* w_in  = (const float*)d_in[2];
  const float* b_in  = (const float*)d_in[3];
  const float* gwq   = (const float*)d_in[4];
  const float* gwk   = (const float*)d_in[5];
  const float* gb    = (const float*)d_in[6];
  const float* wr0   = (const float*)d_in[7];
  const float* wr1   = (const float*)d_in[8];
  const float* wih_c = (const float*)d_in[9];
  const float* whh_c = (const float*)d_in[10];
  const float* bih_c = (const float*)d_in[11];
  const float* bhh_c = (const float*)d_in[12];
  const float* wih_p = (const float*)d_in[13];
  const float* whh_p = (const float*)d_in[14];
  const float* bih_p = (const float*)d_in[15];
  const float* bhh_p = (const float*)d_in[16];
  const float* w1    = (const float*)d_in[17];
  const float* b1    = (const float*)d_in[18];
  const float* w2    = (const float*)d_in[19];
  const float* b2    = (const float*)d_in[20];
  const float* w3    = (const float*)d_in[21];
  const float* b3    = (const float*)d_in[22];
  float* out = (float*)d_out;

  char* ws = (char*)d_ws;
  size_t off = 0;
  auto alloc = [&](size_t bytes)->void*{
    void* p = ws + off;
    off += (bytes + 255) & ~(size_t)255;
    return p;
  };
  f16x2* W_M4 = (f16x2*)alloc((size_t)4*38*1800*4 * sizeof(f16x2));
  f16x2* WrT4 = (f16x2*)alloc((size_t)4*38*600*4  * sizeof(f16x2));
  f16x2* W_14 = (f16x2*)alloc((size_t)318*304*4   * sizeof(f16x2));
  f16x2* W_24 = (f16x2*)alloc((size_t)38*304*4    * sizeof(f16x2));
  float* Hbuf[5];
  for (int i=0;i<5;i++) Hbuf[i] = (float*)alloc((size_t)NROWS*HID*sizeof(float));
  float* pre   = (float*)alloc((size_t)NROWS*1800*sizeof(float));
  float* qd    = (float*)alloc((size_t)NROWS*sizeof(float));
  float* xchg  = (float*)alloc((size_t)64*3600*sizeof(float));
  int*   syncc = (int*)alloc((size_t)4*64*64*sizeof(int));

  {
    const int tot = 4*38*1800*4 + 4*38*600*4;
    convert_kernel<<<(tot+255)/256, 256, 0, stream>>>(whh_c, wih_p, wr0, wr1, W_M4, WrT4);
  }
  {
    const int tot = 318*304*4 + 38*304*4 + 4*64*64;
    convert_head_kernel<<<(tot+255)/256, 256, 0, stream>>>(w1, w2, W_14, W_24, syncc);
  }
  h0_kernel<<<NROWS/16, 256, 0, stream>>>(feat, w_in, b_in, Hbuf[0]);

  for (int l=0;l<4;l++){
    pre_kernel<<<NROWS/16, 256, 0, stream>>>(Hbuf[l], pre, qd,
        wih_c + (size_t)l*900*HID, whh_p + (size_t)l*900*HID,
        bih_c + l*900, bhh_p + l*900, gwq + l*HID);
    scan_kernel<<<256, 512, 0, stream>>>(Hbuf[l], Hbuf[l+1], pre, qd,
        W_M4 + (size_t)l*38*1800*4, WrT4 + (size_t)l*38*600*4,
        bhh_c + l*900, bih_p + l*900, gwk + l*HID, gb, l, spk, xchg, syncc);
  }
  head_kernel<<<NROWS/16, 256, 0, stream>>>(Hbuf[0], Hbuf[1], Hbuf[2], Hbuf[3], Hbuf[4],
      feat, W_14, b1, W_24, b2, w3, b3, out);
}

// Round 4
// 6553.597 us; speedup vs baseline: 3.5037x; 3.5037x over previous
//
#include <hip/hip_runtime.h>
#include <hip/hip_bf16.h>

typedef _Float16 f16x2 __attribute__((ext_vector_type(2)));

#define HID 300
#define NSEQ 64
#define NROWS 4096   // B*N = 64*64

__device__ __forceinline__ float sigm(float x){ return 1.f/(1.f+__expf(-x)); }

__device__ __forceinline__ float fdot2a(f16x2 a, f16x2 b, float c){
#if __has_builtin(__builtin_amdgcn_fdot2)
  return __builtin_amdgcn_fdot2(a, b, c, false);
#else
  return c + (float)a.x*(float)b.x + (float)a.y*(float)b.y;
#endif
}

// ---------------------------------------------------------------------------
// Serial-path weight repack: f32 -> fp16 pairs, [kg][outs][4 pairs] layout.
// W_M4: per layer [38][1800][4]; rows 0..899 = whh_c, 900..1799 = wih_p.
// WrT4: per layer [38][600][4]; row t = d*2+hh (hh=0 -> wr0 row d, 1 -> wr1).
// Cols padded 300->304.
// ---------------------------------------------------------------------------
__global__ void convert_kernel(const float* __restrict__ whh_c, const float* __restrict__ wih_p,
    const float* __restrict__ wr0, const float* __restrict__ wr1,
    f16x2* __restrict__ W_M4, f16x2* __restrict__ WrT4)
{
  const int NA = 4*38*1800*4;
  const int NB = 4*38*600*4;
  for (int idx = blockIdx.x*blockDim.x + threadIdx.x; idx < NA+NB; idx += gridDim.x*blockDim.x){
    if (idx < NA){
      int l    = idx/(38*1800*4);
      int rem  = idx - l*(38*1800*4);
      int kg   = rem/(1800*4);
      int rem2 = rem - kg*(1800*4);
      int o = rem2>>2, s = rem2&3;
      int c = (kg*4+s)*2;
      float v0=0.f, v1=0.f;
      if (c < 300){
        const float* src = (o<900) ? (whh_c + ((size_t)l*900+o)*300)
                                   : (wih_p + ((size_t)l*900+(o-900))*300);
        v0 = src[c]; v1 = src[c+1];
      }
      f16x2 t; t.x=(_Float16)v0; t.y=(_Float16)v1;
      W_M4[idx] = t;
    } else {
      int j    = idx - NA;
      int l    = j/(38*600*4);
      int rem  = j - l*(38*600*4);
      int kg   = rem/(600*4);
      int rem2 = rem - kg*(600*4);
      int t6 = rem2>>2, s = rem2&3;
      int d = t6>>1, hh = t6&1;
      int c = (kg*4+s)*2;
      float v0=0.f, v1=0.f;
      if (c < 300){
        const float* src = hh ? (wr1 + ((size_t)l*300+d)*300)
                              : (wr0 + ((size_t)l*300+d)*300);
        v0 = src[c]; v1 = src[c+1];
      }
      f16x2 t; t.x=(_Float16)v0; t.y=(_Float16)v1;
      WrT4[j] = t;
    }
  }
}

// ---------------------------------------------------------------------------
// Head weight repack.
// W_14: [318 kg][304 o][4 pairs]; seg0..4 = Hcat cols seg*300 (38 kg each),
// seg5..6 = feat cols 1500+(seg-5)*512 (64 kg each).  W_24: [38][304][4].
// ---------------------------------------------------------------------------
__global__ void convert_head_kernel(const float* __restrict__ w1, const float* __restrict__ w2,
    f16x2* __restrict__ W_14, f16x2* __restrict__ W_24)
{
  const int N1 = 318*304*4;
  const int N2 = 38*304*4;
  for (int idx = blockIdx.x*blockDim.x + threadIdx.x; idx < N1+N2; idx += gridDim.x*blockDim.x){
    if (idx < N1){
      int kgg = idx/(304*4);
      int rem = idx - kgg*(304*4);
      int o = rem>>2, s = rem&3;
      int segbase, seglen, kgl;
      if (kgg < 190){ int seg = kgg/38; kgl = kgg - seg*38; segbase = seg*300; seglen = 300; }
      else { int kk = kgg-190; int sf = kk>>6; kgl = kk&63; segbase = 1500 + sf*512; seglen = 512; }
      int c = (kgl*4+s)*2;
      float v0=0.f, v1=0.f;
      if (o < 300 && c < seglen){
        v0 = w1[(size_t)o*2524 + segbase + c];
        if (c+1 < seglen) v1 = w1[(size_t)o*2524 + segbase + c + 1];
      }
      f16x2 t; t.x=(_Float16)v0; t.y=(_Float16)v1;
      W_14[idx] = t;
    } else {
      int j = idx - N1;
      int kg = j/(304*4);
      int rem = j - kg*(304*4);
      int o = rem>>2, s = rem&3;
      int c = (kg*4+s)*2;
      float v0=0.f, v1=0.f;
      if (o < 300 && c < 300){ v0 = w2[(size_t)o*300+c]; v1 = w2[(size_t)o*300+c+1]; }
      f16x2 t; t.x=(_Float16)v0; t.y=(_Float16)v1;
      W_24[j] = t;
    }
  }
}

// ---------------------------------------------------------------------------
// H0 = relu(features @ w_in^T + b_in) : (4096,1024)x(1024,300) -> f32
// ---------------------------------------------------------------------------
__global__ __launch_bounds__(256) void h0_kernel(const float* __restrict__ feat,
    const float* __restrict__ w_in, const float* __restrict__ b_in, float* __restrict__ H0)
{
  const int tid = threadIdx.x;
  const int r0  = blockIdx.x*16;
  __shared__ float X[16*512];
  float acc[2][16];
  #pragma unroll
  for (int a=0;a<2;a++)
    #pragma unroll
    for (int r=0;r<16;r++) acc[a][r]=0.f;

  for (int c=0;c<2;c++){
    for (int t=tid; t<16*512; t+=256){
      int r=t>>9, k=t&511;
      X[t] = feat[(size_t)(r0+r)*1024 + c*512 + k];
    }
    __syncthreads();
    #pragma unroll
    for (int oo=0;oo<2;oo++){
      int o = tid + oo*256;
      if (o < HID){
        const float* wrow = w_in + (size_t)o*1024 + c*512;
        for (int k=0;k<512;k+=4){
          float4 w = *(const float4*)(wrow+k);
          #pragma unroll
          for (int r=0;r<16;r++)
            acc[oo][r] += w.x*X[r*512+k] + w.y*X[r*512+k+1]
                        + w.z*X[r*512+k+2] + w.w*X[r*512+k+3];
        }
      }
    }
    __syncthreads();
  }
  #pragma unroll
  for (int oo=0;oo<2;oo++){
    int o = tid + oo*256;
    if (o < HID){
      float bb = b_in[o];
      for (int r=0;r<16;r++)
        H0[(size_t)(r0+r)*HID + o] = fmaxf(acc[oo][r]+bb, 0.f);
    }
  }
}

// ---------------------------------------------------------------------------
// Per-layer precompute: pre[row][0..899]=wih_c@Hin+bih_c, [900..1799]=whh_p@Hin+bhh_p
// qd[row] = wq . Hin[row].  16 rows per block.
// ---------------------------------------------------------------------------
__global__ __launch_bounds__(256) void pre_kernel(const float* __restrict__ Hin,
    float* __restrict__ pre, float* __restrict__ qd,
    const float* __restrict__ wih_c, const float* __restrict__ whh_p,
    const float* __restrict__ bih_c, const float* __restrict__ bhh_p,
    const float* __restrict__ wq)
{
  const int tid = threadIdx.x;
  const int r0  = blockIdx.x*16;
  __shared__ float X[16*304];
  for (int t=tid; t<16*HID; t+=256){
    int r=t/HID, k=t-r*HID;
    X[r*304+k] = Hin[(size_t)(r0+r)*HID + k];
  }
  __syncthreads();
  for (int o=tid; o<1800; o+=256){
    const float* wrow; float bias;
    if (o < 900){ wrow = wih_c + (size_t)o*HID;        bias = bih_c[o]; }
    else        { wrow = whh_p + (size_t)(o-900)*HID;  bias = bhh_p[o-900]; }
    float acc[16];
    #pragma unroll
    for (int r=0;r<16;r++) acc[r]=0.f;
    for (int k=0;k<HID;k+=4){
      float4 w = *(const float4*)(wrow+k);
      #pragma unroll
      for (int r=0;r<16;r++)
        acc[r] += w.x*X[r*304+k] + w.y*X[r*304+k+1]
                + w.z*X[r*304+k+2] + w.w*X[r*304+k+3];
    }
    #pragma unroll
    for (int r=0;r<16;r++)
      pre[(size_t)(r0+r)*1800 + o] = acc[r] + bias;
  }
  if (tid < 16){
    float s=0.f; const float* x=&X[tid*304];
    for (int k=0;k<HID;k++) s += wq[k]*x[k];
    qd[r0+tid] = s;
  }
}

// ---------------------------------------------------------------------------
// Sequential scan: one workgroup per chain (64 WGs x 1024 thr), 63 steps.
// C/D GEMV streams software-pipelined (lookahead-1, dual-row in D).
// ---------------------------------------------------------------------------
__global__ __launch_bounds__(1024) void scan_kernel(
  const float* __restrict__ Hin, float* __restrict__ Hout,
  const float* __restrict__ pre, const float* __restrict__ qd,
  const f16x2* __restrict__ Wm, const f16x2* __restrict__ Wrt,
  const float* __restrict__ bhh_c, const float* __restrict__ bih_p,
  const float* __restrict__ wk, const float* __restrict__ gat_b, int layer,
  const int* __restrict__ speakers)
{
  __shared__ _Float16 Hh[NSEQ][304];   // fp16 history of H1 rows
  __shared__ float gates[1800];
  __shared__ float Mf[HID];
  __shared__ f16x2 Mh[152];            // fp16 M, padded 300->304
  __shared__ f16x2 u01h[304];          // u0 | u1 pairs, padded
  __shared__ float partM[600];
  __shared__ float wgt[NSEQ];
  __shared__ float kd[NSEQ];
  __shared__ float qs[NSEQ];
  __shared__ float red[320];
  __shared__ int   spk[NSEQ];
  __shared__ int   startA[NSEQ];

  const int tid = threadIdx.x;
  const int b   = blockIdx.x;
  const int base = b*NSEQ;
  const float* preB = pre + (size_t)base*1800;
  const float* HinB = Hin + (size_t)base*HID;
  float* HoutB      = Hout + (size_t)base*HID;
  const uint4* Wm4  = (const uint4*)Wm;
  const uint4* Wr4  = (const uint4*)Wrt;
  const float gb = gat_b[layer];

  float bcr=0,bcz=0,bcn=0,bpr=0,bpz=0,bpn=0,wkv=0;
  if (tid < HID){
    bcr=bhh_c[tid]; bcz=bhh_c[300+tid]; bcn=bhh_c[600+tid];
    bpr=bih_p[tid]; bpz=bih_p[300+tid]; bpn=bih_p[600+tid];
    wkv=wk[tid];
  }
  if (tid < NSEQ){ spk[tid] = speakers[base+tid]; qs[tid] = qd[base+tid]; }
  if (tid >= 300 && tid < 320) red[tid] = 0.f;
  if (tid >= 300 && tid < 304){
    ((_Float16*)Mh)[tid]        = (_Float16)0.f;
    ((_Float16*)u01h)[tid]      = (_Float16)0.f;
    ((_Float16*)u01h)[304+tid]  = (_Float16)0.f;
  }
  __syncthreads();
  if (tid < NSEQ){
    int s = 0;
    for (int j=tid-1; j>=0; --j) if (spk[j]==spk[tid]){ s=j; break; }
    startA[tid] = s;
  }
  // i = 0 : C0 = GRU(x0, 0), P0 = GRU(0, x0)
  if (tid < HID){
    const float* p0 = preB;
    float r  = sigm(p0[tid] + bcr);
    float z  = sigm(p0[300+tid] + bcz);
    float n  = tanhf(p0[600+tid] + r*bcn);
    float C0 = (1.f-z)*n;
    float rp = sigm(bpr + p0[900+tid]);
    float zp = sigm(bpz + p0[1200+tid]);
    float np = tanhf(bpn + rp*p0[1500+tid]);
    float x0 = HinB[tid];
    float P0 = (1.f-zp)*np + zp*x0;
    float h  = C0 + P0;
    HoutB[tid] = h;
    Hh[0][tid] = (_Float16)h;
    red[tid]   = h*wkv;
  }
  __syncthreads();
  if (tid < 64){
    float s = red[tid]+red[tid+64]+red[tid+128]+red[tid+192]+red[tid+256];
    #pragma unroll
    for (int o=32;o>0;o>>=1) s += __shfl_xor(s,o);
    if (tid==0) kd[0]=s;
  }

  for (int i=1; i<NSEQ; ++i){
    // prefetch pre row i + Hin row i (consumed only in GRU phase E)
    float pr0=0,pr1=0,pr2=0,pr3=0,pr4=0,pr5=0,qv=0;
    if (tid < HID){
      const float* p = preB + (size_t)i*1800;
      pr0=p[tid]; pr1=p[300+tid]; pr2=p[600+tid];
      pr3=p[900+tid]; pr4=p[1200+tid]; pr5=p[1500+tid];
      qv = HinB[(size_t)i*HID + tid];
    }
    __syncthreads();   // kd[i-1], Hh[i-1] visible
    // A: masked softmax over window [startA[i], i-1] (one wave)
    if (tid < 64){
      const int st = startA[i];
      const bool in = (tid>=st) && (tid<i);
      const float q = qs[i];
      float a = in ? (q + kd[tid] + gb) : -3.0e38f;
      float m = a;
      #pragma unroll
      for (int o=32;o>0;o>>=1) m = fmaxf(m, __shfl_xor(m,o));
      float e = in ? __expf(a-m) : 0.f;
      float ssum = e;
      #pragma unroll
      for (int o=32;o>0;o>>=1) ssum += __shfl_xor(ssum,o);
      wgt[tid] = e/ssum;
    }
    __syncthreads();
    // B: u0 = sum same-speaker, u1 = sum different-speaker (window is short)
    if (tid < 600){
      const int d  = (tid<300)? tid : (tid-300);
      const int wh = (tid>=300);
      const int st = startA[i]; const int ms = spk[i];
      float u=0.f;
      for (int j=st;j<i;++j){
        float sel = ((spk[j]==ms) != (wh!=0)) ? 1.f : 0.f;
        u += sel*wgt[j]*(float)Hh[j][d];
      }
      ((_Float16*)u01h)[(wh?304:0) + d] = (_Float16)u;
    }
    __syncthreads();
    // C: M = wr0@u0 + wr1@u1 : 600 rows, lookahead-1 pipeline
    if (tid < 600){
      const int hh = tid&1;
      const f16x2* uu = (const f16x2*)u01h + hh*152;
      union U { uint4 u; f16x2 h[4]; };
      U c0, n0;
      c0.u = Wr4[tid];
      float a0=0,a1=0,a2=0,a3=0;
      for (int kg=0;kg<38;kg++){
        if (kg<37) n0.u = Wr4[(size_t)(kg+1)*600 + tid];
        a0=fdot2a(c0.h[0],uu[kg*4+0],a0);
        a1=fdot2a(c0.h[1],uu[kg*4+1],a1);
        a2=fdot2a(c0.h[2],uu[kg*4+2],a2);
        a3=fdot2a(c0.h[3],uu[kg*4+3],a3);
        c0 = n0;
      }
      partM[tid] = (a0+a1)+(a2+a3);
    }
    __syncthreads();
    if (tid < HID){
      float m = partM[2*tid]+partM[2*tid+1];
      Mf[tid]=m; ((_Float16*)Mh)[tid]=(_Float16)m;
    }
    __syncthreads();
    // D: gates = [whh_c ; wih_p] @ M : 1800 rows, dual-row + lookahead-1
    {
      const int o1 = tid;
      const int o2 = tid + 1024;
      const bool has2 = (o2 < 1800);
      union U { uint4 u; f16x2 h[4]; };
      U c0, c1, n0, n1;
      c1.u = uint4{0,0,0,0};
      c0.u = Wm4[o1];
      if (has2) c1.u = Wm4[o2];
      float a0=0,a1=0,a2=0,a3=0, e0=0,e1=0,e2=0,e3=0;
      for (int kg=0;kg<38;kg++){
        if (kg<37){
          n0.u = Wm4[(size_t)(kg+1)*1800 + o1];
          if (has2) n1.u = Wm4[(size_t)(kg+1)*1800 + o2];
        }
        f16x2 m0=Mh[kg*4+0], m1=Mh[kg*4+1], m2=Mh[kg*4+2], m3=Mh[kg*4+3];
        a0=fdot2a(c0.h[0],m0,a0); a1=fdot2a(c0.h[1],m1,a1);
        a2=fdot2a(c0.h[2],m2,a2); a3=fdot2a(c0.h[3],m3,a3);
        if (has2){
          e0=fdot2a(c1.h[0],m0,e0); e1=fdot2a(c1.h[1],m1,e1);
          e2=fdot2a(c1.h[2],m2,e2); e3=fdot2a(c1.h[3],m3,e3);
        }
        c0 = n0;
        if (has2) c1 = n1;
      }
      gates[o1] = (a0+a1)+(a2+a3);
      if (has2) gates[o2] = (e0+e1)+(e2+e3);
    }
    __syncthreads();
    // E: GRU combine, H1[i] = C + P
    if (tid < HID){
      const float M = Mf[tid];
      float r  = sigm(pr0 + gates[tid] + bcr);
      float z  = sigm(pr1 + gates[300+tid] + bcz);
      float n  = tanhf(pr2 + r*(gates[600+tid]+bcn));
      float C  = (1.f-z)*n + z*M;
      float rp = sigm(gates[900+tid]+bpr + pr3);
      float zp = sigm(gates[1200+tid]+bpz + pr4);
      float np = tanhf(gates[1500+tid]+bpn + rp*pr5);
      float P  = (1.f-zp)*np + zp*qv;
      float h  = C + P;
      HoutB[(size_t)i*HID + tid] = h;
      Hh[i][tid] = (_Float16)h;
      red[tid] = h*wkv;
    }
    __syncthreads();
    // F: kd[i] = wk . H1[i]
    if (tid < 64){
      float s = red[tid]+red[tid+64]+red[tid+128]+red[tid+192]+red[tid+256];
      #pragma unroll
      for (int o=32;o>0;o>>=1) s += __shfl_xor(s,o);
      if (tid==0) kd[i]=s;
    }
  }
}

// ---------------------------------------------------------------------------
// Head with fp16-dot2 GEMMs; segments unrolled.
// ---------------------------------------------------------------------------
__global__ __launch_bounds__(256) void head_kernel(
  const float* __restrict__ H0, const float* __restrict__ Hl1,
  const float* __restrict__ Hl2, const float* __restrict__ Hl3,
  const float* __restrict__ Hl4, const float* __restrict__ feat,
  const f16x2* __restrict__ W14, const float* __restrict__ b1,
  const f16x2* __restrict__ W24, const float* __restrict__ b2,
  const float* __restrict__ w3, const float* __restrict__ b3,
  float* __restrict__ out)
{
  const int tid = threadIdx.x;
  const int r0  = blockIdx.x*16;
  __shared__ f16x2 Xh[16*256];
  __shared__ _Float16 h1h[16*304];
  __shared__ float S2[16*304];
  const uint4* W14u = (const uint4*)W14;
  const uint4* W24u = (const uint4*)W24;

  float acc0[16], acc1[16];
  #pragma unroll
  for (int r=0;r<16;r++){ acc0[r]=0.f; acc1[r]=0.f; }
  const int o  = tid;
  const int o2 = tid + 256;
  const bool has2 = (o2 < 300);

  #pragma unroll
  for (int seg=0; seg<7; seg++){
    const float* src = (seg==0)?H0:(seg==1)?Hl1:(seg==2)?Hl2:(seg==3)?Hl3:(seg==4)?Hl4:feat;
    if (seg < 5){
      for (int t=tid; t<16*152; t+=256){
        int r=t/152, p=t-r*152, c=2*p;
        float v0 = (c<300)? src[(size_t)(r0+r)*300 + c] : 0.f;
        float v1 = (c+1<300)? src[(size_t)(r0+r)*300 + c+1] : 0.f;
        f16x2 h; h.x=(_Float16)v0; h.y=(_Float16)v1;
        Xh[r*256+p] = h;
      }
    } else {
      const int cb = (seg-5)*512;
      for (int t=tid; t<16*256; t+=256){
        int r=t>>8, p=t&255;
        float v0 = src[(size_t)(r0+r)*1024 + cb + 2*p];
        float v1 = src[(size_t)(r0+r)*1024 + cb + 2*p+1];
        f16x2 h; h.x=(_Float16)v0; h.y=(_Float16)v1;
        Xh[r*256+p] = h;
      }
    }
    __syncthreads();
    const int kgs = (seg<5)?38:64;
    const int kgo = (seg<5)? seg*38 : 190+(seg-5)*64;
    if (o < 300){
      for (int kg=0; kg<kgs; kg++){
        union { uint4 u; f16x2 h[4]; } a, b;
        a.u = W14u[(size_t)(kgo+kg)*304 + o];
        if (has2) b.u = W14u[(size_t)(kgo+kg)*304 + o2];
        #pragma unroll
        for (int r=0;r<16;r++){
          const f16x2* xp = &Xh[r*256 + kg*4];
          float t0 = fdot2a(a.h[0], xp[0], 0.f);
          t0 = fdot2a(a.h[1], xp[1], t0);
          t0 = fdot2a(a.h[2], xp[2], t0);
          t0 = fdot2a(a.h[3], xp[3], t0);
          acc0[r] += t0;
          if (has2){
            float t1 = fdot2a(b.h[0], xp[0], 0.f);
            t1 = fdot2a(b.h[1], xp[1], t1);
            t1 = fdot2a(b.h[2], xp[2], t1);
            t1 = fdot2a(b.h[3], xp[3], t1);
            acc1[r] += t1;
          }
        }
      }
    }
    __syncthreads();
  }
  if (o < 300){
    float bb = b1[o];
    #pragma unroll
    for (int r=0;r<16;r++) h1h[r*304+o] = (_Float16)fmaxf(acc0[r]+bb, 0.f);
  }
  if (has2){
    float bb = b1[o2];
    #pragma unroll
    for (int r=0;r<16;r++) h1h[r*304+o2] = (_Float16)fmaxf(acc1[r]+bb, 0.f);
  }
  if (tid < 4){
    #pragma unroll
    for (int r=0;r<16;r++) h1h[r*304+300+tid] = (_Float16)0.f;
  }
  __syncthreads();
  // h2 = relu(h1 @ w2^T + b2)
  #pragma unroll
  for (int r=0;r<16;r++){ acc0[r]=0.f; acc1[r]=0.f; }
  if (o < 300){
    for (int kg=0; kg<38; kg++){
      union { uint4 u; f16x2 h[4]; } a, b;
      a.u = W24u[(size_t)kg*304 + o];
      if (has2) b.u = W24u[(size_t)kg*304 + o2];
      #pragma unroll
      for (int r=0;r<16;r++){
        const f16x2* xp = (const f16x2*)&h1h[r*304] + kg*4;
        float t0 = fdot2a(a.h[0], xp[0], 0.f);
        t0 = fdot2a(a.h[1], xp[1], t0);
        t0 = fdot2a(a.h[2], xp[2], t0);
        t0 = fdot2a(a.h[3], xp[3], t0);
        acc0[r] += t0;
        if (has2){
          float t1 = fdot2a(b.h[0], xp[0], 0.f);
          t1 = fdot2a(b.h[1], xp[1], t1);
          t1 = fdot2a(b.h[2], xp[2], t1);
          t1 = fdot2a(b.h[3], xp[3], t1);
          acc1[r] += t1;
        }
      }
    }
  }
  __syncthreads();
  if (o < 300){
    float bb = b2[o];
    #pragma unroll
    for (int r=0;r<16;r++) S2[r*304+o] = fmaxf(acc0[r]+bb, 0.f);
  }
  if (has2){
    float bb = b2[o2];
    #pragma unroll
    for (int r=0;r<16;r++) S2[r*304+o2] = fmaxf(acc1[r]+bb, 0.f);
  }
  __syncthreads();
  // logits (7 per row), f32
  if (tid < 16*7){
    int r = tid/7, c = tid - r*7;
    float s = b3[c];
    const float* wrow = w3 + (size_t)c*HID;
    for (int k=0;k<HID;k++) s += wrow[k]*S2[r*304+k];
    out[(size_t)(r0+r)*7 + c] = s;
  }
}

// ---------------------------------------------------------------------------
extern "C" void kernel_launch(void* const* d_in, const int* in_sizes, int n_in,
                              void* d_out, int out_size, void* d_ws, size_t ws_size,
                              hipStream_t stream)
{
  (void)in_sizes; (void)n_in; (void)out_size; (void)ws_size;
  const float* feat  = (const float*)d_in[0];
  const int*   spk   = (const int*)d_in[1];
  const float* w_in  = (const float*)d_in[2];
  const float* b_in  = (const float*)d_in[3];
  const float* gwq   = (const float*)d_in[4];
  const float* gwk   = (const float*)d_in[5];
  const float* gb    = (const float*)d_in[6];
  const float* wr0   = (const float*)d_in[7];
  const float* wr1   = (const float*)d_in[8];
  const float* wih_c = (const float*)d_in[9];
  const float* whh_c = (const float*)d_in[10];
  const float* bih_c = (const float*)d_in[11];
  const float* bhh_c = (const float*)d_in[12];
  const float* wih_p = (const float*)d_in[13];
  const float* whh_p = (const float*)d_in[14];
  const float* bih_p = (const float*)d_in[15];
  const float* bhh_p = (const float*)d_in[16];
  const float* w1    = (const float*)d_in[17];
  const float* b1    = (const float*)d_in[18];
  const float* w2    = (const float*)d_in[19];
  const float* b2    = (const float*)d_in[20];
  const float* w3    = (const float*)d_in[21];
  const float* b3    = (const float*)d_in[22];
  float* out = (float*)d_out;

  char* ws = (char*)d_ws;
  size_t off = 0;
  auto alloc = [&](size_t bytes)->void*{
    void* p = ws + off;
    off += (bytes + 255) & ~(size_t)255;
    return p;
  };
  f16x2* W_M4 = (f16x2*)alloc((size_t)4*38*1800*4 * sizeof(f16x2));
  f16x2* WrT4 = (f16x2*)alloc((size_t)4*38*600*4  * sizeof(f16x2));
  f16x2* W_14 = (f16x2*)alloc((size_t)318*304*4   * sizeof(f16x2));
  f16x2* W_24 = (f16x2*)alloc((size_t)38*304*4    * sizeof(f16x2));
  float* Hbuf[5];
  for (int i=0;i<5;i++) Hbuf[i] = (float*)alloc((size_t)NROWS*HID*sizeof(float));
  float* pre   = (float*)alloc((size_t)NROWS*1800*sizeof(float));
  float* qd    = (float*)alloc((size_t)NROWS*sizeof(float));

  {
    const int tot = 4*38*1800*4 + 4*38*600*4;
    convert_kernel<<<(tot+255)/256, 256, 0, stream>>>(whh_c, wih_p, wr0, wr1, W_M4, WrT4);
  }
  {
    const int tot = 318*304*4 + 38*304*4;
    convert_head_kernel<<<(tot+255)/256, 256, 0, stream>>>(w1, w2, W_14, W_24);
  }
  h0_kernel<<<NROWS/16, 256, 0, stream>>>(feat, w_in, b_in, Hbuf[0]);

  for (int l=0;l<4;l++){
    pre_kernel<<<NROWS/16, 256, 0, stream>>>(Hbuf[l], pre, qd,
        wih_c + (size_t)l*900*HID, whh_p + (size_t)l*900*HID,
        bih_c + l*900, bhh_p + l*900, gwq + l*HID);
    scan_kernel<<<64, 1024, 0, stream>>>(Hbuf[l], Hbuf[l+1], pre, qd,
        W_M4 + (size_t)l*38*1800*4, WrT4 + (size_t)l*38*600*4,
        bhh_c + l*900, bih_p + l*900, gwk + l*HID, gb, l, spk);
  }
  head_kernel<<<NROWS/16, 256, 0, stream>>>(Hbuf[0], Hbuf[1], Hbuf[2], Hbuf[3], Hbuf[4],
      feat, W_14, b1, W_24, b2, w3, b3, out);
}